// Round 1
// baseline (73.923 us; speedup 1.0000x reference)
//
#include <hip/hip_runtime.h>

// Problem constants (shape (1,1,192,224,192) f32)
#define DD 192
#define HH 224
#define WW 192
#define TOTAL (DD*HH*WW)   // 8,257,536

#define NBLOCKS 2048
#define NTHREADS 256

__global__ __launch_bounds__(NTHREADS) void ngf_main_kernel(
    const float* __restrict__ I, const float* __restrict__ J,
    float* __restrict__ partial)
{
    const float EPS2 = 0.01f;  // 0.1^2
    int tid = blockIdx.x * blockDim.x + threadIdx.x;
    int stride = gridDim.x * blockDim.x;
    float acc = 0.0f;

    for (int idx = tid; idx < TOTAL; idx += stride) {
        int w  = idx % WW;
        int hd = idx / WW;
        int h  = hd % HH;
        int d  = hd / HH;

        int d0 = max(d - 1, 0), d2 = min(d + 1, DD - 1);
        int h0 = max(h - 1, 0), h2 = min(h + 1, HH - 1);
        int w0 = max(w - 1, 0), w2 = min(w + 1, WW - 1);

        // 9 base row offsets (shared between I and J)
        int dI[3] = { d0, d, d2 };
        int hI[3] = { h0, h, h2 };
        int off[3][3];
        #pragma unroll
        for (int a = 0; a < 3; ++a)
            #pragma unroll
            for (int b = 0; b < 3; ++b)
                off[a][b] = (dI[a] * HH + hI[b]) * WW;

        // ---- gradients of I ----
        float Irw[3][3], It[3][3];
        #pragma unroll
        for (int a = 0; a < 3; ++a) {
            #pragma unroll
            for (int b = 0; b < 3; ++b) {
                const float* p = I + off[a][b];
                float v0 = p[w0], v1 = p[w], v2 = p[w2];
                Irw[a][b] = v0 + v1 + v2;
                It[a][b]  = v2 - v0;
            }
        }
        float Ix = 0.5f * (It[0][0]+It[0][1]+It[0][2]
                          +It[1][0]+It[1][1]+It[1][2]
                          +It[2][0]+It[2][1]+It[2][2]);
        float Icd0 = Irw[0][0]+Irw[0][1]+Irw[0][2];
        float Icd2 = Irw[2][0]+Irw[2][1]+Irw[2][2];
        float Ich0 = Irw[0][0]+Irw[1][0]+Irw[2][0];
        float Ich2 = Irw[0][2]+Irw[1][2]+Irw[2][2];
        float Iz = 0.5f * (Icd2 - Icd0);   // varies along d
        float Iy = 0.5f * (Ich2 - Ich0);   // varies along h

        // ---- gradients of J ----
        float Jrw[3][3], Jt[3][3];
        #pragma unroll
        for (int a = 0; a < 3; ++a) {
            #pragma unroll
            for (int b = 0; b < 3; ++b) {
                const float* p = J + off[a][b];
                float v0 = p[w0], v1 = p[w], v2 = p[w2];
                Jrw[a][b] = v0 + v1 + v2;
                Jt[a][b]  = v2 - v0;
            }
        }
        float Jx = 0.5f * (Jt[0][0]+Jt[0][1]+Jt[0][2]
                          +Jt[1][0]+Jt[1][1]+Jt[1][2]
                          +Jt[2][0]+Jt[2][1]+Jt[2][2]);
        float Jcd0 = Jrw[0][0]+Jrw[0][1]+Jrw[0][2];
        float Jcd2 = Jrw[2][0]+Jrw[2][1]+Jrw[2][2];
        float Jch0 = Jrw[0][0]+Jrw[1][0]+Jrw[2][0];
        float Jch2 = Jrw[0][2]+Jrw[1][2]+Jrw[2][2];
        float Jz = 0.5f * (Jcd2 - Jcd0);
        float Jy = 0.5f * (Jch2 - Jch0);

        // ---- NGF ----
        float Imag = Ix*Ix + Iy*Iy + Iz*Iz + EPS2;
        float Jmag = Jx*Jx + Jy*Jy + Jz*Jz + EPS2;
        float dot  = Ix*Jx + Iy*Jy + Iz*Jz;
        acc += 1.0f - (dot * dot) / (Imag * Jmag);
    }

    // wave (64-lane) shuffle reduce
    #pragma unroll
    for (int o = 32; o > 0; o >>= 1)
        acc += __shfl_down(acc, o, 64);

    __shared__ float smem[NTHREADS / 64];
    int lane = threadIdx.x & 63;
    int wid  = threadIdx.x >> 6;
    if (lane == 0) smem[wid] = acc;
    __syncthreads();
    if (threadIdx.x == 0) {
        float s = 0.0f;
        #pragma unroll
        for (int i = 0; i < NTHREADS / 64; ++i) s += smem[i];
        partial[blockIdx.x] = s;
    }
}

__global__ __launch_bounds__(256) void ngf_reduce_kernel(
    const float* __restrict__ partial, float* __restrict__ out)
{
    double acc = 0.0;
    for (int i = threadIdx.x; i < NBLOCKS; i += blockDim.x)
        acc += (double)partial[i];

    #pragma unroll
    for (int o = 32; o > 0; o >>= 1)
        acc += __shfl_down(acc, o, 64);

    __shared__ double smem[4];
    int lane = threadIdx.x & 63;
    int wid  = threadIdx.x >> 6;
    if (lane == 0) smem[wid] = acc;
    __syncthreads();
    if (threadIdx.x == 0) {
        double s = smem[0] + smem[1] + smem[2] + smem[3];
        out[0] = (float)(s / (double)TOTAL);
    }
}

extern "C" void kernel_launch(void* const* d_in, const int* in_sizes, int n_in,
                              void* d_out, int out_size, void* d_ws, size_t ws_size,
                              hipStream_t stream)
{
    const float* I = (const float*)d_in[0];
    const float* J = (const float*)d_in[1];
    float* out = (float*)d_out;
    float* partial = (float*)d_ws;   // NBLOCKS floats = 8 KB

    ngf_main_kernel<<<NBLOCKS, NTHREADS, 0, stream>>>(I, J, partial);
    ngf_reduce_kernel<<<1, 256, 0, stream>>>(partial, out);
}

// Round 2
// 42.162 us; speedup vs baseline: 1.7533x; 1.7533x over previous
//
#include <hip/hip_runtime.h>

// shape (1,1,192,224,192) f32
#define DD 192
#define HH 224
#define WW 192
#define PLANE (HH*WW)          // 43008
#define TOTAL (DD*HH*WW)       // 8257536

#define WC 48                  // WW/4 chunks per row
#define DSEG 8                 // d-outputs per thread
#define NSEG (DD/DSEG)         // 24
#define COLS (HH*WC)           // 10752
#define NTHREADS 256
#define NBLOCKS ((COLS*NSEG)/NTHREADS)   // 1008

struct Plane { float PT[4]; float PS[4]; float HD[4]; };

__global__ __launch_bounds__(NTHREADS) void ngf_main_kernel(
    const float* __restrict__ I, const float* __restrict__ J,
    float* __restrict__ partial)
{
    const float EPS2 = 0.04f;  // (2*0.1)^2 — 0.5 Sobel factor folded out

    int tid = blockIdx.x * NTHREADS + threadIdx.x;
    int wc  = tid % WC;
    int t   = tid / WC;
    int h   = t % HH;
    int seg = t / HH;
    int ds  = seg * DSEG;
    int w0  = wc * 4;

    int h0 = max(h - 1, 0), h2 = min(h + 1, HH - 1);
    int rowoff[3] = { h0 * WW, h * WW, h2 * WW };
    int oL = (w0 == 0) ? 0 : -1;
    int oR = (w0 == WW - 4) ? 3 : 4;

    const float* colI = I + w0;
    const float* colJ = J + w0;

    // per-plane aggregates: PT = sum of w-diffs over 3 rows; PS = sum of
    // 3-wide row sums over 3 rows; HD = rowsum(h+1) - rowsum(h-1)
    auto mk_plane = [&](const float* __restrict__ col, int dp) -> Plane {
        Plane P;
        const float* base = col + dp * PLANE;
        float s[3][4], tt[3][4];
        #pragma unroll
        for (int b = 0; b < 3; ++b) {
            const float* p = base + rowoff[b];
            float4 v = *reinterpret_cast<const float4*>(p);
            float vl = p[oL], vr = p[oR];
            s[b][0] = vl  + v.x + v.y;
            s[b][1] = v.x + v.y + v.z;
            s[b][2] = v.y + v.z + v.w;
            s[b][3] = v.z + v.w + vr;
            tt[b][0] = v.y - vl;
            tt[b][1] = v.z - v.x;
            tt[b][2] = v.w - v.y;
            tt[b][3] = vr  - v.z;
        }
        #pragma unroll
        for (int j = 0; j < 4; ++j) {
            P.PT[j] = tt[0][j] + tt[1][j] + tt[2][j];
            P.PS[j] = s[0][j] + s[1][j] + s[2][j];
            P.HD[j] = s[2][j] - s[0][j];
        }
        return P;
    };

    Plane pI[3], pJ[3];
    // prologue: slot0 <- plane ds-1 (clamped), slot1 <- plane ds
    {
        int dm = max(ds - 1, 0);
        pI[0] = mk_plane(colI, dm);
        pJ[0] = mk_plane(colJ, dm);
        pI[1] = mk_plane(colI, ds);
        pJ[1] = mk_plane(colJ, ds);
    }

    float acc = 0.0f;
    #pragma unroll
    for (int k = 0; k < DSEG; ++k) {
        int dn = min(ds + k + 1, DD - 1);
        int sa = k % 3, sb = (k + 1) % 3, sc = (k + 2) % 3;
        pI[sc] = mk_plane(colI, dn);
        pJ[sc] = mk_plane(colJ, dn);

        #pragma unroll
        for (int j = 0; j < 4; ++j) {
            float Ix = pI[sa].PT[j] + pI[sb].PT[j] + pI[sc].PT[j];
            float Iy = pI[sa].HD[j] + pI[sb].HD[j] + pI[sc].HD[j];
            float Iz = pI[sc].PS[j] - pI[sa].PS[j];
            float Jx = pJ[sa].PT[j] + pJ[sb].PT[j] + pJ[sc].PT[j];
            float Jy = pJ[sa].HD[j] + pJ[sb].HD[j] + pJ[sc].HD[j];
            float Jz = pJ[sc].PS[j] - pJ[sa].PS[j];

            float Imag = fmaf(Ix, Ix, fmaf(Iy, Iy, fmaf(Iz, Iz, EPS2)));
            float Jmag = fmaf(Jx, Jx, fmaf(Jy, Jy, fmaf(Jz, Jz, EPS2)));
            float dot  = fmaf(Ix, Jx, fmaf(Iy, Jy, Iz * Jz));
            acc += 1.0f - (dot * dot) * __builtin_amdgcn_rcpf(Imag * Jmag);
        }
    }

    // wave reduce (64 lanes)
    #pragma unroll
    for (int o = 32; o > 0; o >>= 1)
        acc += __shfl_down(acc, o, 64);

    __shared__ float smem[NTHREADS / 64];
    int lane = threadIdx.x & 63;
    int wid  = threadIdx.x >> 6;
    if (lane == 0) smem[wid] = acc;
    __syncthreads();
    if (threadIdx.x == 0) {
        float s = 0.0f;
        #pragma unroll
        for (int i = 0; i < NTHREADS / 64; ++i) s += smem[i];
        partial[blockIdx.x] = s;
    }
}

__global__ __launch_bounds__(256) void ngf_reduce_kernel(
    const float* __restrict__ partial, float* __restrict__ out)
{
    double acc = 0.0;
    for (int i = threadIdx.x; i < NBLOCKS; i += blockDim.x)
        acc += (double)partial[i];

    #pragma unroll
    for (int o = 32; o > 0; o >>= 1)
        acc += __shfl_down(acc, o, 64);

    __shared__ double smem[4];
    int lane = threadIdx.x & 63;
    int wid  = threadIdx.x >> 6;
    if (lane == 0) smem[wid] = acc;
    __syncthreads();
    if (threadIdx.x == 0) {
        double s = smem[0] + smem[1] + smem[2] + smem[3];
        out[0] = (float)(s / (double)TOTAL);
    }
}

extern "C" void kernel_launch(void* const* d_in, const int* in_sizes, int n_in,
                              void* d_out, int out_size, void* d_ws, size_t ws_size,
                              hipStream_t stream)
{
    const float* I = (const float*)d_in[0];
    const float* J = (const float*)d_in[1];
    float* out = (float*)d_out;
    float* partial = (float*)d_ws;   // NBLOCKS floats

    ngf_main_kernel<<<NBLOCKS, NTHREADS, 0, stream>>>(I, J, partial);
    ngf_reduce_kernel<<<1, 256, 0, stream>>>(partial, out);
}